// Round 1
// baseline (111.060 us; speedup 1.0000x reference)
//
#include <hip/hip_runtime.h>
#include <hip/hip_bf16.h>

#define BB 8
#define SS 1024
#define IN_DIM 1024
#define NOUT 1024
#define DHEAD 256
#define MTOT (BB*SS)

typedef __bf16 bf16;
typedef __bf16 bf16x8 __attribute__((ext_vector_type(8)));
typedef __bf16 bf16x4 __attribute__((ext_vector_type(4)));
typedef float f32x4 __attribute__((ext_vector_type(4)));

// ws layout (bytes)
#define QK_OFF   0                 // 8*2*2*1024*256 bf16 = 16 MiB
#define XB_OFF   (16u*1024*1024)   // 8192*1024 bf16     = 16 MiB
#define WB_OFF   (32u*1024*1024)   // 1024*1024 bf16     =  2 MiB
#define RT_OFF   (34u*1024*1024)   // 1024*128 float2    =  1 MiB
#define ACC_OFF  (35u*1024*1024)   // 2 floats

__device__ __forceinline__ void gload_lds16(const void* g, void* l) {
  __builtin_amdgcn_global_load_lds(
      (const __attribute__((address_space(1))) unsigned int*)g,
      (__attribute__((address_space(3))) unsigned int*)l, 16, 0, 0);
}

__global__ void cvt_bf16_kernel(const float* __restrict__ in, bf16* __restrict__ out, int n4) {
  int i = blockIdx.x * blockDim.x + threadIdx.x;
  if (i >= n4) return;
  float4 v = ((const float4*)in)[i];
  bf16x4 o;
  o.x = (bf16)v.x; o.y = (bf16)v.y; o.z = (bf16)v.z; o.w = (bf16)v.w;
  ((bf16x4*)out)[i] = o;
}

__global__ void rope_table_kernel(float2* __restrict__ rt) {
  int i = blockIdx.x * blockDim.x + threadIdx.x;   // S*128 = 131072
  int s = i >> 7, f = i & 127;
  float inv = powf(15.0f, -2.0f * (float)f / 256.0f);
  float ang = (float)s * inv;
  rt[i] = make_float2(cosf(ang), sinf(ang));
}

// C = X(bf16) @ W(bf16)^T + b, fused RoPE, write Q/K bf16 -> ws
// QK layout: [b][h][qk][s][d], qk: 0=Q 1=K
__global__ __launch_bounds__(256) void gemm_rope_kernel(
    const bf16* __restrict__ Xb, const bf16* __restrict__ Wb,
    const float* __restrict__ bias, const float2* __restrict__ rt,
    bf16* __restrict__ QK) {
  __shared__ __align__(16) bf16 lA[128 * 32];
  __shared__ __align__(16) bf16 lB[128 * 32];
  const int tid = threadIdx.x;
  const int lane = tid & 63, w = tid >> 6;
  const int wr = w >> 1, wc = w & 1;
  const int fr = lane & 15, fq = lane >> 4;
  const int m0 = blockIdx.y * 128, n0 = blockIdx.x * 128;
  const int c0 = tid, c1 = tid + 256;

  f32x4 acc[4][4] = {};

  for (int k0 = 0; k0 < IN_DIM; k0 += 32) {
    gload_lds16(Xb + (size_t)(m0 + (c0 >> 2)) * IN_DIM + k0 + (c0 & 3) * 8, &lA[c0 * 8]);
    gload_lds16(Xb + (size_t)(m0 + (c1 >> 2)) * IN_DIM + k0 + (c1 & 3) * 8, &lA[c1 * 8]);
    gload_lds16(Wb + (size_t)(n0 + (c0 >> 2)) * IN_DIM + k0 + (c0 & 3) * 8, &lB[c0 * 8]);
    gload_lds16(Wb + (size_t)(n0 + (c1 >> 2)) * IN_DIM + k0 + (c1 & 3) * 8, &lB[c1 * 8]);
    __syncthreads();  // drains vmcnt -> tiles visible
    bf16x8 af[4], bv[4];
#pragma unroll
    for (int i = 0; i < 4; i++) af[i] = *(const bf16x8*)&lA[(wr * 64 + i * 16 + fr) * 32 + fq * 8];
#pragma unroll
    for (int j = 0; j < 4; j++) bv[j] = *(const bf16x8*)&lB[(wc * 64 + j * 16 + fr) * 32 + fq * 8];
#pragma unroll
    for (int i = 0; i < 4; i++)
#pragma unroll
      for (int j = 0; j < 4; j++)
        acc[i][j] = __builtin_amdgcn_mfma_f32_16x16x32_bf16(af[i], bv[j], acc[i][j], 0, 0, 0);
    __syncthreads();  // reads done before next-stage overwrite
  }

  // epilogue: bias + RoPE + bf16 store
#pragma unroll
  for (int i = 0; i < 4; i++) {
    const int mb = m0 + wr * 64 + i * 16 + fq * 4;
#pragma unroll
    for (int j2 = 0; j2 < 4; j2++) {
      const int n = n0 + wc * 64 + j2 * 16 + fr;
      const float bvn = bias[n];
#pragma unroll
      for (int j = 0; j < 4; j++) {
        float v = acc[i][j2][j] + bvn;
        float p = __shfl_xor(v, 1);          // partner column n^1 (same rows)
        float rot = (n & 1) ? p : -p;        // d even: -x[d+1]; d odd: +x[d-1]
        const int m_ = mb + j;
        const int s = m_ & (SS - 1);
        const int d = n & (DHEAD - 1);
        float2 cs = rt[s * 128 + (d >> 1)];
        float o = v * cs.x + rot * cs.y;
        const int bidx = m_ >> 10;
        const int h = n >> 9, qk = (n >> 8) & 1;
        QK[(size_t)((bidx * 2 + h) * 2 + qk) * (SS * DHEAD) + s * DHEAD + d] = (bf16)o;
      }
    }
  }
}

// logits[b,m,n,h] = Q[b,h,m,:].K[b,h,n,:]  (both heads per tile) + fused NLL reduction
__global__ __launch_bounds__(256) void logits_loss_kernel(
    const bf16* __restrict__ QK, const int* __restrict__ labels,
    const int* __restrict__ masks, float* __restrict__ out,
    float* __restrict__ accbuf) {
  __shared__ __align__(16) bf16 lQ[2][128 * 32];
  __shared__ __align__(16) bf16 lK[2][128 * 32];
  __shared__ float red[8];
  const int tid = threadIdx.x;
  const int lane = tid & 63, w = tid >> 6;
  const int wr = w >> 1, wc = w & 1;
  const int fr = lane & 15, fq = lane >> 4;
  const int b = blockIdx.z;
  const int m0 = blockIdx.y * 128, n0 = blockIdx.x * 128;
  const int c0 = tid, c1 = tid + 256;

  const bf16* Qb0 = QK + (size_t)((b * 2 + 0) * 2 + 0) * (SS * DHEAD);
  const bf16* Qb1 = QK + (size_t)((b * 2 + 1) * 2 + 0) * (SS * DHEAD);
  const bf16* Kb0 = QK + (size_t)((b * 2 + 0) * 2 + 1) * (SS * DHEAD);
  const bf16* Kb1 = QK + (size_t)((b * 2 + 1) * 2 + 1) * (SS * DHEAD);

  f32x4 acc[2][4][4] = {};

  for (int k0 = 0; k0 < DHEAD; k0 += 32) {
#pragma unroll
    for (int t4 = 0; t4 < 4; ++t4) {
      const bf16* src = (t4 == 0) ? Qb0 : (t4 == 1) ? Qb1 : (t4 == 2) ? Kb0 : Kb1;
      bf16* dst = (t4 == 0) ? &lQ[0][0] : (t4 == 1) ? &lQ[1][0] : (t4 == 2) ? &lK[0][0] : &lK[1][0];
      const int r0 = (t4 < 2) ? m0 : n0;
      gload_lds16(src + (size_t)(r0 + (c0 >> 2)) * DHEAD + k0 + (c0 & 3) * 8, dst + c0 * 8);
      gload_lds16(src + (size_t)(r0 + (c1 >> 2)) * DHEAD + k0 + (c1 & 3) * 8, dst + c1 * 8);
    }
    __syncthreads();
#pragma unroll
    for (int h = 0; h < 2; ++h) {
      const bf16* q = h ? &lQ[1][0] : &lQ[0][0];
      const bf16* kk = h ? &lK[1][0] : &lK[0][0];
      bf16x8 af[4], bv[4];
#pragma unroll
      for (int i = 0; i < 4; i++) af[i] = *(const bf16x8*)(q + (wr * 64 + i * 16 + fr) * 32 + fq * 8);
#pragma unroll
      for (int i = 0; i < 4; i++) bv[i] = *(const bf16x8*)(kk + (wc * 64 + i * 16 + fr) * 32 + fq * 8);
#pragma unroll
      for (int i = 0; i < 4; i++)
#pragma unroll
        for (int j = 0; j < 4; j++)
          acc[h][i][j] = __builtin_amdgcn_mfma_f32_16x16x32_bf16(af[i], bv[j], acc[h][i][j], 0, 0, 0);
    }
    __syncthreads();
  }

  float s_sum = 0.f, s_cnt = 0.f;
#pragma unroll
  for (int i = 0; i < 4; i++) {
    const int mb = m0 + wr * 64 + i * 16 + fq * 4;
#pragma unroll
    for (int j2 = 0; j2 < 4; j2++) {
      const int n = n0 + wc * 64 + j2 * 16 + fr;
#pragma unroll
      for (int j = 0; j < 4; j++) {
        const int m_ = mb + j;
        float l0 = acc[0][i][j2][j];
        float l1 = acc[1][i][j2][j];
        size_t p = ((size_t)(b * SS + m_) * SS + n);
        out[1 + 2 * p] = l0;
        out[2 + 2 * p] = l1;
        int lab = labels[p];
        int mk = masks[p];
        float mx = fmaxf(l0, l1);
        float lse = mx + logf(expf(l0 - mx) + expf(l1 - mx));
        float nll = lse - (lab ? l1 : l0);
        if (mk == 1) { s_sum += nll; s_cnt += 1.0f; }
      }
    }
  }
#pragma unroll
  for (int off = 32; off; off >>= 1) {
    s_sum += __shfl_down(s_sum, off);
    s_cnt += __shfl_down(s_cnt, off);
  }
  if (lane == 0) { red[w] = s_sum; red[4 + w] = s_cnt; }
  __syncthreads();
  if (tid == 0) {
    atomicAdd(&accbuf[0], red[0] + red[1] + red[2] + red[3]);
    atomicAdd(&accbuf[1], red[4] + red[5] + red[6] + red[7]);
  }
}

__global__ void finalize_kernel(const float* __restrict__ accbuf, float* __restrict__ out) {
  out[0] = accbuf[0] / accbuf[1];
}

extern "C" void kernel_launch(void* const* d_in, const int* in_sizes, int n_in,
                              void* d_out, int out_size, void* d_ws, size_t ws_size,
                              hipStream_t stream) {
  const float* X = (const float*)d_in[0];
  const int* labels = (const int*)d_in[1];
  const int* masks = (const int*)d_in[2];
  const float* W = (const float*)d_in[3];
  const float* bias = (const float*)d_in[4];
  float* out = (float*)d_out;
  char* ws = (char*)d_ws;

  bf16* QK = (bf16*)(ws + QK_OFF);
  bf16* Xb = (bf16*)(ws + XB_OFF);
  bf16* Wb = (bf16*)(ws + WB_OFF);
  float2* rt = (float2*)(ws + RT_OFF);
  float* acc = (float*)(ws + ACC_OFF);

  hipMemsetAsync(acc, 0, 8, stream);
  cvt_bf16_kernel<<<(MTOT * IN_DIM / 4 + 255) / 256, 256, 0, stream>>>(X, Xb, MTOT * IN_DIM / 4);
  cvt_bf16_kernel<<<(NOUT * IN_DIM / 4 + 255) / 256, 256, 0, stream>>>(W, Wb, NOUT * IN_DIM / 4);
  rope_table_kernel<<<(SS * 128) / 256, 256, 0, stream>>>(rt);
  gemm_rope_kernel<<<dim3(NOUT / 128, MTOT / 128), 256, 0, stream>>>(Xb, Wb, bias, rt, QK);
  logits_loss_kernel<<<dim3(SS / 128, SS / 128, BB), 256, 0, stream>>>(QK, labels, masks, out, acc);
  finalize_kernel<<<1, 1, 0, stream>>>(acc, out);
}